// Round 2
// baseline (229.667 us; speedup 1.0000x reference)
//
#include <hip/hip_runtime.h>
#include <math.h>

#ifndef M_PI
#define M_PI 3.14159265358979323846
#endif

// Problem constants (setup_inputs: audio (32,2,441000) f32, scalar int params)
#define T_LEN  441000
#define L      32                        // samples per lane
#define WARM   8                         // warm-up lanes per wave (8*32 = 256 samples, r^256 ~ 1e-11)
#define SEG_W  ((64 - WARM) * L)         // 1792 stored samples per independent wave
#define WPC    ((T_LEN + SEG_W - 1) / SEG_W)   // 247 waves per channel
#define BLOCK  256                       // 4 independent waves per block (no barriers, no LDS)
#define BLK_X  ((WPC + 3) / 4)           // 62 blocks in x per channel

// d_ws layout (floats): [0..4] = b0,b1,b2,a1,a2 ; [5+4j .. 8+4j] = M^(32*2^j) row-major, j=0..5
// (scan over 64 lanes of 32-sample segments needs M^32, M^64, ..., M^1024)

__device__ __forceinline__ double log_scale(double v, double mn, double mx) {
    v = fmin(fmax(v, mn), mx);
    double lmin = log(fmax(mn, 1e-6));
    double lmax = log(mx);
    double nrm = (log(fmax(v, 1e-6)) - lmin) / (lmax - lmin);
    return nrm * (mx - mn) + mn;
}

__global__ void eq_setup_kernel(const int* __restrict__ f_in,
                                const int* __restrict__ g_in,
                                const int* __restrict__ q_in,
                                float* __restrict__ ws) {
    // Single thread; all double math to match the numpy coefficient path.
    double f = log_scale((double)f_in[0], 20.0, 20000.0);
    double g = fmin(fmax((double)g_in[0], -30.0), 30.0);
    double Q = log_scale((double)q_in[0], 0.1, 30.0);
    double w0 = 2.0 * M_PI * f / 44100.0;
    double A  = pow(10.0, g / 40.0);
    double al = sin(w0) / (2.0 * Q);
    double ca = cos(w0);
    double b0 = 1.0 + al * A;
    double b1 = -2.0 * ca;
    double b2 = 1.0 - al * A;
    double a0 = 1.0 + al / A;
    double B0 = b0 / a0, B1 = b1 / a0, B2 = b2 / a0;
    double A1 = b1 / a0, A2 = (1.0 - al / A) / a0;
    ws[0] = (float)B0; ws[1] = (float)B1; ws[2] = (float)B2;
    ws[3] = (float)A1; ws[4] = (float)A2;

    // M = [[-a1, -a2], [1, 0]]; compute M^32 .. M^1024 by repeated squaring (double).
    double p11 = -A1, p12 = -A2, p21 = 1.0, p22 = 0.0;
    for (int i = 0; i < 5; ++i) {            // -> M^32
        double s11 = p11 * p11 + p12 * p21;
        double s12 = p11 * p12 + p12 * p22;
        double s21 = p21 * p11 + p22 * p21;
        double s22 = p21 * p12 + p22 * p22;
        p11 = s11; p12 = s12; p21 = s21; p22 = s22;
    }
    for (int j = 0; j < 6; ++j) {            // store M^(32*2^j), j=0..5
        ws[5 + 4 * j + 0] = (float)p11;
        ws[5 + 4 * j + 1] = (float)p12;
        ws[5 + 4 * j + 2] = (float)p21;
        ws[5 + 4 * j + 3] = (float)p22;
        double s11 = p11 * p11 + p12 * p21;
        double s12 = p11 * p12 + p12 * p22;
        double s21 = p21 * p11 + p22 * p21;
        double s22 = p21 * p12 + p22 * p22;
        p11 = s11; p12 = s12; p21 = s21; p22 = s22;
    }
}

// Fully wave-independent: no __shared__, no __syncthreads, single shfl scan.
// __launch_bounds__(256, 8): cap VGPR at 64 -> 8 waves/SIMD (32 waves/CU).
__global__ __launch_bounds__(BLOCK, 8) void eq_main_kernel(
        const float* __restrict__ x,
        const float* __restrict__ ws,
        float* __restrict__ y) {
    const int tid  = threadIdx.x;
    const int lane = tid & 63;
    const int wv   = tid >> 6;
    const int wave = blockIdx.x * (BLOCK / 64) + wv;   // wave index within channel, 0..247
    if (wave * SEG_W >= T_LEN) return;                 // padding wave (only #247)
    const int ch   = blockIdx.y;

    const float b0 = ws[0], b1 = ws[1], b2 = ws[2], a1 = ws[3], a2 = ws[4];

    const float* __restrict__ xc = x + (size_t)ch * T_LEN;
    float*       __restrict__ yc = y + (size_t)ch * T_LEN;

    // Lane's 32-sample segment; first WARM lanes are zero-state warm-up (not stored).
    const int base = wave * SEG_W - WARM * L + lane * L;   // multiple of 32 (can be negative)

    // ---- Load 32 samples + 2 preceding (zeros outside [0, T_LEN)). 9 dwordx4 in flight.
    float xv[L], xm1, xm2;
    if (base >= 4 && base + L <= T_LEN) {
        const float4 vm = *reinterpret_cast<const float4*>(xc + base - 4);
        xm2 = vm.z; xm1 = vm.w;
#pragma unroll
        for (int q = 0; q < L / 4; ++q) {
            const float4 v = *reinterpret_cast<const float4*>(xc + base + 4 * q);
            xv[4 * q + 0] = v.x; xv[4 * q + 1] = v.y;
            xv[4 * q + 2] = v.z; xv[4 * q + 3] = v.w;
        }
    } else {
#pragma unroll
        for (int k = 0; k < L; ++k) {
            const int idx = base + k;
            xv[k] = (idx >= 0 && idx < T_LEN) ? xc[idx] : 0.f;
        }
        xm1 = (base - 1 >= 0 && base - 1 < T_LEN) ? xc[base - 1] : 0.f;
        xm2 = (base - 2 >= 0 && base - 2 < T_LEN) ? xc[base - 2] : 0.f;
    }

    // ---- Zero-state local pass: FIR t computed on the fly (recomputed later; keeps VGPR low).
    // c = (y_n, y_{n-1}) after this lane's 32 samples starting from state 0.
    float c0 = 0.f, c1 = 0.f;
    {
        float xk1 = xm1, xk2 = xm2;
#pragma unroll
        for (int k = 0; k < L; ++k) {
            const float xk = xv[k];
            const float t  = fmaf(b0, xk, fmaf(b1, xk1, b2 * xk2));
            const float yn = fmaf(-a1, c0, fmaf(-a2, c1, t));
            c1 = c0; c0 = yn;
            xk2 = xk1; xk1 = xk;
        }
    }

    // ---- Single inclusive wave scan: compose affine offsets; level j uses A = M^(32*2^j).
#pragma unroll
    for (int j = 0; j < 6; ++j) {
        const float m11 = ws[5 + 4 * j + 0], m12 = ws[5 + 4 * j + 1];
        const float m21 = ws[5 + 4 * j + 2], m22 = ws[5 + 4 * j + 3];
        const float d0 = __shfl_up(c0, 1u << j);
        const float d1 = __shfl_up(c1, 1u << j);
        if (lane >= (1 << j)) {
            c0 = fmaf(m11, d0, fmaf(m12, d1, c0));
            c1 = fmaf(m21, d0, fmaf(m22, d1, c1));
        }
    }

    // ---- Exclusive shift: exact incoming state per lane (wave starts from zero state).
    float s0 = __shfl_up(c0, 1);
    float s1 = __shfl_up(c1, 1);
    if (lane == 0) { s0 = 0.f; s1 = 0.f; }

    // ---- Final pass: exact recurrence from s; FIR recomputed (identical rounding).
    if (lane >= WARM && base < T_LEN) {
        float p0 = s0, p1 = s1;                    // (y_{n-1}, y_{n-2})
        float xk1 = xm1, xk2 = xm2;
        if (base + L <= T_LEN) {
#pragma unroll
            for (int q = 0; q < L / 4; ++q) {
                float ov[4];
#pragma unroll
                for (int r = 0; r < 4; ++r) {
                    const float xk = xv[4 * q + r];
                    const float t  = fmaf(b0, xk, fmaf(b1, xk1, b2 * xk2));
                    const float yn = fmaf(-a1, p0, fmaf(-a2, p1, t));
                    p1 = p0; p0 = yn;
                    xk2 = xk1; xk1 = xk;
                    ov[r] = yn;
                }
                *reinterpret_cast<float4*>(yc + base + 4 * q) =
                    make_float4(ov[0], ov[1], ov[2], ov[3]);
            }
        } else {
#pragma unroll
            for (int k = 0; k < L; ++k) {
                const float xk = xv[k];
                const float t  = fmaf(b0, xk, fmaf(b1, xk1, b2 * xk2));
                const float yn = fmaf(-a1, p0, fmaf(-a2, p1, t));
                p1 = p0; p0 = yn;
                xk2 = xk1; xk1 = xk;
                if (base + k < T_LEN) yc[base + k] = yn;
            }
        }
    }
}

extern "C" void kernel_launch(void* const* d_in, const int* in_sizes, int n_in,
                              void* d_out, int out_size, void* d_ws, size_t ws_size,
                              hipStream_t stream) {
    const float* x = (const float*)d_in[0];
    const int*   f = (const int*)d_in[1];
    const int*   g = (const int*)d_in[2];
    const int*   q = (const int*)d_in[3];
    float*       y  = (float*)d_out;
    float*       ws = (float*)d_ws;

    eq_setup_kernel<<<1, 1, 0, stream>>>(f, g, q, ws);

    const int nch = in_sizes[0] / T_LEN;   // 64 for this problem
    dim3 grid(BLK_X, nch);
    eq_main_kernel<<<grid, dim3(BLOCK), 0, stream>>>(x, ws, y);
}

// Round 4
// 215.375 us; speedup vs baseline: 1.0664x; 1.0664x over previous
//
#include <hip/hip_runtime.h>
#include <math.h>

#ifndef M_PI
#define M_PI 3.14159265358979323846
#endif

// Problem constants (setup_inputs: audio (32,2,441000) f32, scalar int params)
#define T_LEN      441000
#define L          16                          // samples per lane
#define WARM_LANES 16                          // 256 warm samples per wave (r^256 ~ 1e-11)
#define OUT_W      ((64 - WARM_LANES) * L)     // 768 stored samples per wave
#define WPC        ((T_LEN + OUT_W - 1) / OUT_W)   // 575 waves per channel
#define BLOCK      256                         // 4 independent waves; no barriers, no LDS
#define BLK_X      ((WPC + 3) / 4)             // 144 blocks in x per channel

// d_ws layout (floats):
//   [0..4]            b0,b1,b2,a1,a2
//   [5+4j .. 8+4j]    M^(16*2^j) row-major, j=0..5          (scan levels)
//   [29+2k, 30+2k]    first row of M^(k+1), k=0..15         (output correction)

__device__ __forceinline__ double log_scale(double v, double mn, double mx) {
    v = fmin(fmax(v, mn), mx);
    double lmin = log(fmax(mn, 1e-6));
    double lmax = log(mx);
    double nrm = (log(fmax(v, 1e-6)) - lmin) / (lmax - lmin);
    return nrm * (mx - mn) + mn;
}

__global__ void eq_setup_kernel(const int* __restrict__ f_in,
                                const int* __restrict__ g_in,
                                const int* __restrict__ q_in,
                                float* __restrict__ ws) {
    // Single thread; all double math to match the numpy coefficient path.
    double f = log_scale((double)f_in[0], 20.0, 20000.0);
    double g = fmin(fmax((double)g_in[0], -30.0), 30.0);
    double Q = log_scale((double)q_in[0], 0.1, 30.0);
    double w0 = 2.0 * M_PI * f / 44100.0;
    double A  = pow(10.0, g / 40.0);
    double al = sin(w0) / (2.0 * Q);
    double ca = cos(w0);
    double b0 = 1.0 + al * A;
    double b1 = -2.0 * ca;
    double b2 = 1.0 - al * A;
    double a0 = 1.0 + al / A;
    double B0 = b0 / a0, B1 = b1 / a0, B2 = b2 / a0;
    double A1 = b1 / a0, A2 = (1.0 - al / A) / a0;
    ws[0] = (float)B0; ws[1] = (float)B1; ws[2] = (float)B2;
    ws[3] = (float)A1; ws[4] = (float)A2;

    // M = [[-a1, -a2], [1, 0]] acting on (y_n, y_{n-1}).
    const double m11 = -A1, m12 = -A2, m21 = 1.0, m22 = 0.0;

    // Scan matrices: M^16 .. M^512 by repeated squaring (double).
    double p11 = m11, p12 = m12, p21 = m21, p22 = m22;
    for (int i = 0; i < 4; ++i) {            // -> M^16
        double s11 = p11 * p11 + p12 * p21;
        double s12 = p11 * p12 + p12 * p22;
        double s21 = p21 * p11 + p22 * p21;
        double s22 = p21 * p12 + p22 * p22;
        p11 = s11; p12 = s12; p21 = s21; p22 = s22;
    }
    for (int j = 0; j < 6; ++j) {            // store M^(16*2^j), j=0..5
        ws[5 + 4 * j + 0] = (float)p11;
        ws[5 + 4 * j + 1] = (float)p12;
        ws[5 + 4 * j + 2] = (float)p21;
        ws[5 + 4 * j + 3] = (float)p22;
        double s11 = p11 * p11 + p12 * p21;
        double s12 = p11 * p12 + p12 * p22;
        double s21 = p21 * p11 + p22 * p21;
        double s22 = p21 * p12 + p22 * p22;
        p11 = s11; p12 = s12; p21 = s21; p22 = s22;
    }

    // Correction rows: first row of M^(k+1), k=0..15.
    // y_exact[k] = y_local[k] + (M^(k+1))_11 * s0 + (M^(k+1))_12 * s1,
    // where s = (y_-1, y_-2) is the lane's incoming state.
    double q11 = m11, q12 = m12, q21 = m21, q22 = m22;   // = M^1
    for (int k = 0; k < 16; ++k) {
        ws[29 + 2 * k] = (float)q11;
        ws[30 + 2 * k] = (float)q12;
        // Q <- M * Q
        const double n11 = m11 * q11 + m12 * q21;
        const double n12 = m11 * q12 + m12 * q22;
        const double n21 = q11;                 // m21*q11 + m22*q21 = q11
        const double n22 = q12;
        q11 = n11; q12 = n12; q21 = n21; q22 = n22;
    }
}

// Wave-independent, single-pass over x (x is consumed immediately -> nothing for the
// compiler to rematerialize via reloads), single shfl scan, linear output correction.
__global__ __launch_bounds__(BLOCK, 6) void eq_main_kernel(
        const float* __restrict__ x,
        const float* __restrict__ ws,
        float* __restrict__ y) {
    const int tid  = threadIdx.x;
    const int lane = tid & 63;
    const int wv   = tid >> 6;
    const int wave = blockIdx.x * (BLOCK / 64) + wv;   // 0..574 active
    if (wave >= WPC) return;                            // wave-uniform exit
    const int ch = blockIdx.y;

    const float b0 = ws[0], b1 = ws[1], b2 = ws[2], a1 = ws[3], a2 = ws[4];

    const float* __restrict__ xc = x + (size_t)ch * T_LEN;
    float*       __restrict__ yc = y + (size_t)ch * T_LEN;

    // Lane's 16-sample segment; first WARM_LANES lanes are warm-up (not stored).
    const int base = wave * OUT_W - WARM_LANES * L + lane * L;   // mult of 16, can be <0

    // ---- Load 16 samples + 2 preceding (zeros outside [0, T_LEN)).
    float xv[L], xm1, xm2;
    if (base >= 4 && base + L <= T_LEN) {
        const float4 vm = *reinterpret_cast<const float4*>(xc + base - 4);
        xm2 = vm.z; xm1 = vm.w;
        const float4 v0 = *reinterpret_cast<const float4*>(xc + base + 0);
        const float4 v1 = *reinterpret_cast<const float4*>(xc + base + 4);
        const float4 v2 = *reinterpret_cast<const float4*>(xc + base + 8);
        const float4 v3 = *reinterpret_cast<const float4*>(xc + base + 12);
        xv[0]=v0.x;  xv[1]=v0.y;  xv[2]=v0.z;  xv[3]=v0.w;
        xv[4]=v1.x;  xv[5]=v1.y;  xv[6]=v1.z;  xv[7]=v1.w;
        xv[8]=v2.x;  xv[9]=v2.y;  xv[10]=v2.z; xv[11]=v2.w;
        xv[12]=v3.x; xv[13]=v3.y; xv[14]=v3.z; xv[15]=v3.w;
    } else {
#pragma unroll
        for (int k = 0; k < L; ++k) {
            const int idx = base + k;
            xv[k] = (idx >= 0 && idx < T_LEN) ? xc[idx] : 0.f;
        }
        xm1 = (base - 1 >= 0 && base - 1 < T_LEN) ? xc[base - 1] : 0.f;
        xm2 = (base - 2 >= 0 && base - 2 < T_LEN) ? xc[base - 2] : 0.f;
    }

    // ---- Single fused pass: FIR + zero-state IIR; record local outputs yl[k].
    // x is used exactly once, immediately — no later pass can force a reload.
    float yl[L];
    float c0 = 0.f, c1 = 0.f;                  // (y_n, y_{n-1}) zero-state
    {
        float xk1 = xm1, xk2 = xm2;
#pragma unroll
        for (int k = 0; k < L; ++k) {
            const float xk = xv[k];
            const float t  = fmaf(b0, xk, fmaf(b1, xk1, b2 * xk2));
            const float yn = fmaf(-a1, c0, fmaf(-a2, c1, t));
            c1 = c0; c0 = yn;
            xk2 = xk1; xk1 = xk;
            yl[k] = yn;
        }
    }

    // ---- Inclusive affine wave scan; level j composes with A = M^(16*2^j).
#pragma unroll
    for (int j = 0; j < 6; ++j) {
        const float m11 = ws[5 + 4 * j + 0], m12 = ws[5 + 4 * j + 1];
        const float m21 = ws[5 + 4 * j + 2], m22 = ws[5 + 4 * j + 3];
        const float d0 = __shfl_up(c0, 1u << j);
        const float d1 = __shfl_up(c1, 1u << j);
        if (lane >= (1 << j)) {
            c0 = fmaf(m11, d0, fmaf(m12, d1, c0));
            c1 = fmaf(m21, d0, fmaf(m22, d1, c1));
        }
    }

    // ---- Exclusive shift: s = exact incoming state (y_-1, y_-2) for this lane.
    float s0 = __shfl_up(c0, 1);
    float s1 = __shfl_up(c1, 1);
    if (lane == 0) { s0 = 0.f; s1 = 0.f; }

    // ---- Output correction (fully parallel, 2 FMAs/sample) + stores.
    if (lane >= WARM_LANES && base < T_LEN) {
        if (base + L <= T_LEN) {
#pragma unroll
            for (int q = 0; q < L / 4; ++q) {
                float o[4];
#pragma unroll
                for (int r = 0; r < 4; ++r) {
                    const int k = 4 * q + r;
                    o[r] = fmaf(ws[29 + 2 * k], s0, fmaf(ws[30 + 2 * k], s1, yl[k]));
                }
                *reinterpret_cast<float4*>(yc + base + 4 * q) =
                    make_float4(o[0], o[1], o[2], o[3]);
            }
        } else {
#pragma unroll
            for (int k = 0; k < L; ++k)
                if (base + k < T_LEN)
                    yc[base + k] = fmaf(ws[29 + 2 * k], s0, fmaf(ws[30 + 2 * k], s1, yl[k]));
        }
    }
}

extern "C" void kernel_launch(void* const* d_in, const int* in_sizes, int n_in,
                              void* d_out, int out_size, void* d_ws, size_t ws_size,
                              hipStream_t stream) {
    const float* x = (const float*)d_in[0];
    const int*   f = (const int*)d_in[1];
    const int*   g = (const int*)d_in[2];
    const int*   q = (const int*)d_in[3];
    float*       y  = (float*)d_out;
    float*       ws = (float*)d_ws;

    eq_setup_kernel<<<1, 1, 0, stream>>>(f, g, q, ws);

    const int nch = in_sizes[0] / T_LEN;   // 64 for this problem
    dim3 grid(BLK_X, nch);
    eq_main_kernel<<<grid, dim3(BLOCK), 0, stream>>>(x, ws, y);
}

// Round 5
// 213.000 us; speedup vs baseline: 1.0782x; 1.0112x over previous
//
#include <hip/hip_runtime.h>
#include <math.h>

#ifndef M_PI
#define M_PI 3.14159265358979323846
#endif

// Problem constants (setup_inputs: audio (32,2,441000) f32, scalar int params)
#define T_LEN      441000
#define L          32                        // samples per lane (= one 128-B LDS row)
#define WARM_ROWS  8                         // 256 warm samples per wave (r^256 ~ 1e-11)
#define ROWS       64                        // rows per wave window
#define OUT_W      ((ROWS - WARM_ROWS) * L)  // 1792 stored samples per wave
#define WPC        ((T_LEN + OUT_W - 1) / OUT_W)   // 247 waves per channel
#define BLOCK      256                       // 4 independent waves; no barriers
#define WAVES_PB   (BLOCK / 64)
#define BLK_X      ((WPC + WAVES_PB - 1) / WAVES_PB)   // 62

// d_ws layout (floats):
//   [0..4]            b0,b1,b2,a1,a2
//   [5+4j .. 8+4j]    M^(32*2^j) row-major, j=0..5          (scan levels)
//   [29+2k, 30+2k]    first row of M^(k+1), k=0..31         (output correction)

__device__ __forceinline__ double log_scale(double v, double mn, double mx) {
    v = fmin(fmax(v, mn), mx);
    double lmin = log(fmax(mn, 1e-6));
    double lmax = log(mx);
    double nrm = (log(fmax(v, 1e-6)) - lmin) / (lmax - lmin);
    return nrm * (mx - mn) + mn;
}

__global__ void eq_setup_kernel(const int* __restrict__ f_in,
                                const int* __restrict__ g_in,
                                const int* __restrict__ q_in,
                                float* __restrict__ ws) {
    // Single thread; all double math to match the numpy coefficient path.
    double f = log_scale((double)f_in[0], 20.0, 20000.0);
    double g = fmin(fmax((double)g_in[0], -30.0), 30.0);
    double Q = log_scale((double)q_in[0], 0.1, 30.0);
    double w0 = 2.0 * M_PI * f / 44100.0;
    double A  = pow(10.0, g / 40.0);
    double al = sin(w0) / (2.0 * Q);
    double ca = cos(w0);
    double b0 = 1.0 + al * A;
    double b1 = -2.0 * ca;
    double b2 = 1.0 - al * A;
    double a0 = 1.0 + al / A;
    double B0 = b0 / a0, B1 = b1 / a0, B2 = b2 / a0;
    double A1 = b1 / a0, A2 = (1.0 - al / A) / a0;
    ws[0] = (float)B0; ws[1] = (float)B1; ws[2] = (float)B2;
    ws[3] = (float)A1; ws[4] = (float)A2;

    // M = [[-a1, -a2], [1, 0]] acting on (y_n, y_{n-1}).
    const double m11 = -A1, m12 = -A2, m21 = 1.0, m22 = 0.0;

    // Scan matrices: M^32 .. M^1024 by repeated squaring (double).
    double p11 = m11, p12 = m12, p21 = m21, p22 = m22;
    for (int i = 0; i < 5; ++i) {            // -> M^32
        double s11 = p11 * p11 + p12 * p21;
        double s12 = p11 * p12 + p12 * p22;
        double s21 = p21 * p11 + p22 * p21;
        double s22 = p21 * p12 + p22 * p22;
        p11 = s11; p12 = s12; p21 = s21; p22 = s22;
    }
    for (int j = 0; j < 6; ++j) {            // store M^(32*2^j), j=0..5
        ws[5 + 4 * j + 0] = (float)p11;
        ws[5 + 4 * j + 1] = (float)p12;
        ws[5 + 4 * j + 2] = (float)p21;
        ws[5 + 4 * j + 3] = (float)p22;
        double s11 = p11 * p11 + p12 * p21;
        double s12 = p11 * p12 + p12 * p22;
        double s21 = p21 * p11 + p22 * p21;
        double s22 = p21 * p12 + p22 * p22;
        p11 = s11; p12 = s12; p21 = s21; p22 = s22;
    }

    // Correction rows: first row of M^(k+1), k=0..31.
    // y_exact[k] = y_local[k] + (M^(k+1))_11 * s0 + (M^(k+1))_12 * s1,
    // where s = (y_-1, y_-2) is the lane's incoming state.
    double q11 = m11, q12 = m12, q21 = m21, q22 = m22;   // = M^1
    for (int k = 0; k < L; ++k) {
        ws[29 + 2 * k] = (float)q11;
        ws[30 + 2 * k] = (float)q12;
        // Q <- M * Q
        const double n11 = m11 * q11 + m12 * q21;
        const double n12 = m11 * q12 + m12 * q22;
        q21 = q11; q22 = q12;
        q11 = n11; q12 = n12;
    }
}

// Wave-independent. ALL global memory traffic is fully coalesced (lane i touches
// bytes [16i,16i+16) of a contiguous 1KB line per instruction); the strided
// per-lane view is produced via a per-wave private LDS buffer with XOR-swizzled
// 16B chunks (chunk ^= row&7) so every LDS phase is at the 8-dword/bank floor.
// No __syncthreads: each wave owns its LDS slice; in-wave DS ordering + compiler
// alias-based lgkmcnt waits are sufficient.
__global__ __launch_bounds__(BLOCK, 4) void eq_main_kernel(
        const float* __restrict__ x,
        const float* __restrict__ ws,
        float* __restrict__ y) {
    __shared__ float4 smem[WAVES_PB][ROWS * 8];   // 4 x 8 KiB = 32 KiB

    const int tid  = threadIdx.x;
    const int lane = tid & 63;
    const int wv   = tid >> 6;
    const int wave = blockIdx.x * WAVES_PB + wv;   // 0..246 active
    if (wave >= WPC) return;                        // wave-uniform exit
    const int ch = blockIdx.y;

    const float* __restrict__ xc = x + (size_t)ch * T_LEN;
    float*       __restrict__ yc = y + (size_t)ch * T_LEN;

    const int obase = wave * OUT_W;            // first stored sample
    const int wbase = obase - WARM_ROWS * L;   // window start (can be -256)
    float4* S = smem[wv];

    // ---- Phase 1: coalesced global -> LDS (swizzled). 8 instrs, 1KB/lane-line each.
#pragma unroll
    for (int c = 0; c < 8; ++c) {
        const int q  = (c << 6) + lane;        // quad index in window, 0..511
        const int g0 = wbase + (q << 2);       // global float index of quad
        float4 v;
        if (g0 >= 0 && g0 + 4 <= T_LEN) {
            v = *reinterpret_cast<const float4*>(xc + g0);
        } else {
            float e[4];
#pragma unroll
            for (int j = 0; j < 4; ++j) {
                const int idx = g0 + j;
                e[j] = (idx >= 0 && idx < T_LEN) ? xc[idx] : 0.f;
            }
            v = make_float4(e[0], e[1], e[2], e[3]);
        }
        const int rr = q >> 3;                 // row 0..63
        const int ck = q & 7;                  // 16B chunk in row
        S[(rr << 3) + (ck ^ (rr & 7))] = v;
    }

    // ---- Phase 2: each lane reads its own row (lane l = samples [wbase+32l, +32)).
    float xv[L];
#pragma unroll
    for (int c = 0; c < 8; ++c) {
        const float4 v = S[(lane << 3) + (c ^ (lane & 7))];
        xv[4 * c + 0] = v.x; xv[4 * c + 1] = v.y;
        xv[4 * c + 2] = v.z; xv[4 * c + 3] = v.w;
    }
    // Preceding 2 samples: neighbor lane's tail via shfl; lane 0 from global (guarded).
    float pm1 = __shfl_up(xv[31], 1);
    float pm2 = __shfl_up(xv[30], 1);
    if (lane == 0) {
        pm1 = (wbase - 1 >= 0) ? xc[wbase - 1] : 0.f;
        pm2 = (wbase - 2 >= 0) ? xc[wbase - 2] : 0.f;
    }

    const float b0 = ws[0], b1 = ws[1], b2 = ws[2], a1 = ws[3], a2 = ws[4];

    // ---- Fused local pass: FIR + zero-state IIR; record local outputs yl[k].
    float yl[L];
    float c0 = 0.f, c1 = 0.f;                  // (y_n, y_{n-1}) zero-state
    {
        float xk1 = pm1, xk2 = pm2;
#pragma unroll
        for (int k = 0; k < L; ++k) {
            const float xk = xv[k];
            const float t  = fmaf(b0, xk, fmaf(b1, xk1, b2 * xk2));
            const float yn = fmaf(-a1, c0, fmaf(-a2, c1, t));
            c1 = c0; c0 = yn;
            xk2 = xk1; xk1 = xk;
            yl[k] = yn;
        }
    }

    // ---- Inclusive affine wave scan; level j composes with A = M^(32*2^j).
#pragma unroll
    for (int j = 0; j < 6; ++j) {
        const float m11 = ws[5 + 4 * j + 0], m12 = ws[5 + 4 * j + 1];
        const float m21 = ws[5 + 4 * j + 2], m22 = ws[5 + 4 * j + 3];
        const float d0 = __shfl_up(c0, 1u << j);
        const float d1 = __shfl_up(c1, 1u << j);
        if (lane >= (1 << j)) {
            c0 = fmaf(m11, d0, fmaf(m12, d1, c0));
            c1 = fmaf(m21, d0, fmaf(m22, d1, c1));
        }
    }

    // ---- Exclusive shift: s = exact incoming state (y_-1, y_-2) for this lane.
    float s0 = __shfl_up(c0, 1);
    float s1 = __shfl_up(c1, 1);
    if (lane == 0) { s0 = 0.f; s1 = 0.f; }

    // ---- Phase 3: correction (2 FMAs/sample, fully parallel) + write back to own row.
    // Overwrites input rows AFTER all phase-2 reads issued (in-wave order); LLVM
    // cannot remat the phase-2 loads across these aliasing stores.
#pragma unroll
    for (int c = 0; c < 8; ++c) {
        float o[4];
#pragma unroll
        for (int r = 0; r < 4; ++r) {
            const int k = 4 * c + r;
            o[r] = fmaf(ws[29 + 2 * k], s0, fmaf(ws[30 + 2 * k], s1, yl[k]));
        }
        S[(lane << 3) + (c ^ (lane & 7))] = make_float4(o[0], o[1], o[2], o[3]);
    }

    // ---- Phase 4: coalesced LDS -> global stores (rows 8..63 = non-warm). 7 instrs.
#pragma unroll
    for (int c = 0; c < 7; ++c) {
        const int q  = (c << 6) + lane;            // output quad 0..447
        const int rr = WARM_ROWS + (q >> 3);       // buffer row 8..63
        const float4 o = S[(rr << 3) + ((q & 7) ^ (rr & 7))];
        const int g0 = obase + (q << 2);
        if (g0 + 4 <= T_LEN) {
            *reinterpret_cast<float4*>(yc + g0) = o;
        } else if (g0 < T_LEN) {
            const float e[4] = {o.x, o.y, o.z, o.w};
#pragma unroll
            for (int j = 0; j < 4; ++j)
                if (g0 + j < T_LEN) yc[g0 + j] = e[j];
        }
    }
}

extern "C" void kernel_launch(void* const* d_in, const int* in_sizes, int n_in,
                              void* d_out, int out_size, void* d_ws, size_t ws_size,
                              hipStream_t stream) {
    const float* x = (const float*)d_in[0];
    const int*   f = (const int*)d_in[1];
    const int*   g = (const int*)d_in[2];
    const int*   q = (const int*)d_in[3];
    float*       y  = (float*)d_out;
    float*       ws = (float*)d_ws;

    eq_setup_kernel<<<1, 1, 0, stream>>>(f, g, q, ws);

    const int nch = in_sizes[0] / T_LEN;   // 64 for this problem
    dim3 grid(BLK_X, nch);
    eq_main_kernel<<<grid, dim3(BLOCK), 0, stream>>>(x, ws, y);
}